// Round 1
// baseline (1061.051 us; speedup 1.0000x reference)
//
#include <hip/hip_runtime.h>

#define N_DATES 252
#define M_FACTORS 8
#define N_SIMS 65536

// One thread per sim. Thread walks all 252 dates sequentially (cumsum is a
// loop-carried register accumulation), loading z[n, 0..7, s] with a 2-date
// double-buffered register prefetch so HBM latency hides under the 8x8 matvec
// + stores of the previous date. cov/var addresses are wave-uniform -> scalar
// cache. Traffic is exactly 1x read of z + 1x write of out.
__global__ __launch_bounds__(64)
void evo_lognormal_kernel(const float* __restrict__ cov,
                          const float* __restrict__ var,
                          const float* __restrict__ z,
                          float* __restrict__ out) {
    const int s = blockIdx.x * 64 + threadIdx.x;   // sim index, grid covers exactly N_SIMS
    const float* zp = z + s;
    float* op = out + s;

    float acc[M_FACTORS];
#pragma unroll
    for (int i = 0; i < M_FACTORS; ++i) acc[i] = 0.0f;

    float bufA[M_FACTORS];
    float bufB[M_FACTORS];

    // preload date 0 into bufA
#pragma unroll
    for (int j = 0; j < M_FACTORS; ++j)
        bufA[j] = zp[(size_t)j * N_SIMS];

    // N_DATES = 252 is even: process dates in pairs (even -> bufA, odd -> bufB)
    for (int n = 0; n < N_DATES; n += 2) {
        // prefetch date n+1 into bufB (n+1 <= 251 always)
        {
            const float* znext = zp + (size_t)(n + 1) * M_FACTORS * N_SIMS;
#pragma unroll
            for (int j = 0; j < M_FACTORS; ++j)
                bufB[j] = znext[(size_t)j * N_SIMS];
        }

        // compute + store date n from bufA
        {
            const float* covn = cov + (size_t)n * (M_FACTORS * M_FACTORS);
            const float* varn = var + (size_t)n * M_FACTORS;
            float* on = op + (size_t)n * M_FACTORS * N_SIMS;
#pragma unroll
            for (int i = 0; i < M_FACTORS; ++i) {
                float d = -0.5f * varn[i];
#pragma unroll
                for (int j = 0; j < M_FACTORS; ++j)
                    d = fmaf(covn[i * M_FACTORS + j], bufA[j], d);
                acc[i] += d;
                on[(size_t)i * N_SIMS] = acc[i];
            }
        }

        // prefetch date n+2 into bufA
        if (n + 2 < N_DATES) {
            const float* znext = zp + (size_t)(n + 2) * M_FACTORS * N_SIMS;
#pragma unroll
            for (int j = 0; j < M_FACTORS; ++j)
                bufA[j] = znext[(size_t)j * N_SIMS];
        }

        // compute + store date n+1 from bufB
        {
            const int n1 = n + 1;
            const float* covn = cov + (size_t)n1 * (M_FACTORS * M_FACTORS);
            const float* varn = var + (size_t)n1 * M_FACTORS;
            float* on = op + (size_t)n1 * M_FACTORS * N_SIMS;
#pragma unroll
            for (int i = 0; i < M_FACTORS; ++i) {
                float d = -0.5f * varn[i];
#pragma unroll
                for (int j = 0; j < M_FACTORS; ++j)
                    d = fmaf(covn[i * M_FACTORS + j], bufB[j], d);
                acc[i] += d;
                on[(size_t)i * N_SIMS] = acc[i];
            }
        }
    }
}

extern "C" void kernel_launch(void* const* d_in, const int* in_sizes, int n_in,
                              void* d_out, int out_size, void* d_ws, size_t ws_size,
                              hipStream_t stream) {
    const float* cov = (const float*)d_in[0];  // [252, 8, 8] f32
    const float* var = (const float*)d_in[1];  // [252, 8]    f32
    const float* z   = (const float*)d_in[2];  // [252, 8, 65536] f32
    float* out = (float*)d_out;                // [252, 8, 65536] f32

    dim3 block(64);
    dim3 grid(N_SIMS / 64);  // 1024 blocks = 1024 waves = 4 waves/CU
    evo_lognormal_kernel<<<grid, block, 0, stream>>>(cov, var, z, out);
}

// Round 4
// 1060.619 us; speedup vs baseline: 1.0004x; 1.0004x over previous
//
#include <hip/hip_runtime.h>

#define N_DATES 252
#define M_FACTORS 8
#define N_SIMS 65536
#define SIMS2 (N_SIMS / 2)      // float2 per thread
#define CHUNKS 12
#define DPC 21                  // dates per chunk: 12 * 21 = 252
#define BLK 256
#define BLOCKS_PER_CHUNK (SIMS2 / BLK)   // 128

// Per-date body: 8x8 matvec on a named register buffer, accumulate into acc.
__device__ __forceinline__
void date_body(const float* __restrict__ cov, const float* __restrict__ var,
               int n, const float2 (&buf)[M_FACTORS], float2 (&acc)[M_FACTORS]) {
    const float* covn = cov + (size_t)n * (M_FACTORS * M_FACTORS);
    const float* varn = var + (size_t)n * M_FACTORS;
#pragma unroll
    for (int i = 0; i < M_FACTORS; ++i) {
        float dx = -0.5f * varn[i];
        float dy = dx;
#pragma unroll
        for (int j = 0; j < M_FACTORS; ++j) {
            const float w = covn[i * M_FACTORS + j];
            dx = fmaf(w, buf[j].x, dx);
            dy = fmaf(w, buf[j].y, dy);
        }
        acc[i].x += dx;
        acc[i].y += dy;
    }
}

__device__ __forceinline__
void load_date(const float2* __restrict__ z2, int n, int s2, float2 (&buf)[M_FACTORS]) {
    const size_t base = ((size_t)n * M_FACTORS) * SIMS2 + s2;
#pragma unroll
    for (int j = 0; j < M_FACTORS; ++j)
        buf[j] = z2[base + (size_t)j * SIMS2];
}

// ---------------- Kernel 1: per-chunk dW totals ----------------
// totals[c, i, s] = sum_{n in chunk c} ( sum_j cov[n,i,j]*z[n,j,s] - 0.5*var[n,i] )
__global__ __launch_bounds__(BLK)
void k1_chunk_totals(const float* __restrict__ cov,
                     const float* __restrict__ var,
                     const float2* __restrict__ z2,
                     float2* __restrict__ totals2) {
    const int c = blockIdx.x / BLOCKS_PER_CHUNK;
    const int lb = blockIdx.x % BLOCKS_PER_CHUNK;
    const int s2 = lb * BLK + threadIdx.x;          // float2-sim index
    const int n0 = c * DPC;

    float2 acc[M_FACTORS];
#pragma unroll
    for (int i = 0; i < M_FACTORS; ++i) acc[i] = make_float2(0.f, 0.f);

    float2 bufA[M_FACTORS], bufB[M_FACTORS];
    load_date(z2, n0, s2, bufA);

    // 20 dates in pairs (even->bufA, odd->bufB), then 1 tail date (n0+20).
#pragma unroll
    for (int p = 0; p < (DPC - 1) / 2; ++p) {
        const int n = n0 + 2 * p;
        load_date(z2, n + 1, s2, bufB);           // prefetch odd
        date_body(cov, var, n, bufA, acc);
        load_date(z2, n + 2, s2, bufA);           // prefetch next even (n+2 <= n0+20, valid)
        date_body(cov, var, n + 1, bufB, acc);
    }
    date_body(cov, var, n0 + DPC - 1, bufA, acc); // tail (already loaded)

#pragma unroll
    for (int i = 0; i < M_FACTORS; ++i)
        totals2[((size_t)c * M_FACTORS + i) * SIMS2 + s2] = acc[i];
}

// ---------------- Kernel 2: in-place exclusive scan over chunks ----------------
// Each thread owns one (factor, float2-sim) column across all 12 chunks.
__global__ __launch_bounds__(BLK)
void k2_scan(float2* __restrict__ totals2) {
    const int t = blockIdx.x * BLK + threadIdx.x;   // in [0, 8*SIMS2)
    const int i = t / SIMS2;
    const int s2 = t % SIMS2;
    float2 run = make_float2(0.f, 0.f);
#pragma unroll
    for (int c = 0; c < CHUNKS; ++c) {
        const size_t idx = ((size_t)c * M_FACTORS + i) * SIMS2 + s2;
        float2 v = totals2[idx];
        totals2[idx] = run;
        run.x += v.x;
        run.y += v.y;
    }
}

// ---------------- Kernel 3: local cumsum + prefix, write output ----------------
__global__ __launch_bounds__(BLK)
void k3_emit(const float* __restrict__ cov,
             const float* __restrict__ var,
             const float2* __restrict__ z2,
             const float2* __restrict__ totals2,  // exclusive prefixes now
             float2* __restrict__ out2) {
    const int c = blockIdx.x / BLOCKS_PER_CHUNK;
    const int lb = blockIdx.x % BLOCKS_PER_CHUNK;
    const int s2 = lb * BLK + threadIdx.x;
    const int n0 = c * DPC;

    float2 acc[M_FACTORS];
#pragma unroll
    for (int i = 0; i < M_FACTORS; ++i)
        acc[i] = totals2[((size_t)c * M_FACTORS + i) * SIMS2 + s2];

    float2 bufA[M_FACTORS], bufB[M_FACTORS];
    load_date(z2, n0, s2, bufA);

#pragma unroll
    for (int p = 0; p < (DPC - 1) / 2; ++p) {
        const int n = n0 + 2 * p;
        load_date(z2, n + 1, s2, bufB);
        date_body(cov, var, n, bufA, acc);
        {   // store date n
            float2* on = out2 + ((size_t)n * M_FACTORS) * SIMS2 + s2;
#pragma unroll
            for (int i = 0; i < M_FACTORS; ++i) on[(size_t)i * SIMS2] = acc[i];
        }
        load_date(z2, n + 2, s2, bufA);
        date_body(cov, var, n + 1, bufB, acc);
        {   // store date n+1
            float2* on = out2 + ((size_t)(n + 1) * M_FACTORS) * SIMS2 + s2;
#pragma unroll
            for (int i = 0; i < M_FACTORS; ++i) on[(size_t)i * SIMS2] = acc[i];
        }
    }
    {   // tail date
        const int n = n0 + DPC - 1;
        date_body(cov, var, n, bufA, acc);
        float2* on = out2 + ((size_t)n * M_FACTORS) * SIMS2 + s2;
#pragma unroll
        for (int i = 0; i < M_FACTORS; ++i) on[(size_t)i * SIMS2] = acc[i];
    }
}

extern "C" void kernel_launch(void* const* d_in, const int* in_sizes, int n_in,
                              void* d_out, int out_size, void* d_ws, size_t ws_size,
                              hipStream_t stream) {
    const float* cov = (const float*)d_in[0];   // [252, 8, 8]
    const float* var = (const float*)d_in[1];   // [252, 8]
    const float2* z2 = (const float2*)d_in[2];  // [252, 8, 65536] viewed as float2
    float2* out2 = (float2*)d_out;
    float2* totals2 = (float2*)d_ws;            // [12, 8, SIMS2] float2 = 25.2 MB

    dim3 blk(BLK);
    k1_chunk_totals<<<dim3(CHUNKS * BLOCKS_PER_CHUNK), blk, 0, stream>>>(cov, var, z2, totals2);
    k2_scan<<<dim3((M_FACTORS * SIMS2) / BLK), blk, 0, stream>>>(totals2);
    k3_emit<<<dim3(CHUNKS * BLOCKS_PER_CHUNK), blk, 0, stream>>>(cov, var, z2, totals2, out2);
}